// Round 7
// baseline (1874.093 us; speedup 1.0000x reference)
//
#include <hip/hip_runtime.h>
#include <stdint.h>

#define HID 512
#define NH 8
#define HD 64
#define BB 4
#define SS 2048

typedef unsigned short u16;
typedef __attribute__((ext_vector_type(8))) short short8;
typedef __attribute__((ext_vector_type(4))) float f32x4;
typedef __attribute__((ext_vector_type(4))) _Float16 f16x4;
typedef __attribute__((ext_vector_type(2))) unsigned int uint2v;

#define MFMA16(a, b, c) __builtin_amdgcn_mfma_f32_16x16x32_bf16((a), (b), (c), 0, 0, 0)
#define MFMAH16(a, b, c) __builtin_amdgcn_mfma_f32_16x16x16f16((a), (b), (c), 0, 0, 0)

// s_waitcnt encodings: lgkmcnt(15)=0xF00 | expcnt(7)=0x70 | vmcnt low4
#define WAIT_VM4() __builtin_amdgcn_s_waitcnt(0xF74)
#define WAIT_VM3() __builtin_amdgcn_s_waitcnt(0xF73)
#define PIPE_BARRIER() do { asm volatile("" ::: "memory"); \
  __builtin_amdgcn_s_barrier(); asm volatile("" ::: "memory"); } while (0)

__device__ __forceinline__ u16 f2bf(float f) {
  union { float f; uint32_t u; } v; v.f = f;
  return (u16)((v.u + 0x7fffu + ((v.u >> 16) & 1u)) >> 16);
}

__device__ __forceinline__ u16 f2h(float f) {
  _Float16 h = (_Float16)f;
  return __builtin_bit_cast(u16, h);
}

__device__ __forceinline__ void gl_lds16(const u16* g, u16* l) {
  __builtin_amdgcn_global_load_lds(
      (const __attribute__((address_space(1))) unsigned int*)g,
      (__attribute__((address_space(3))) unsigned int*)l, 16, 0, 0);
}

// ---------------------------------------------------------------- prep
__global__ void prep(const float* __restrict__ x,
                     const float* __restrict__ w0, const float* __restrict__ w1,
                     const float* __restrict__ w2, const float* __restrict__ w3,
                     u16* __restrict__ xb,
                     u16* __restrict__ o0, u16* __restrict__ o1,
                     u16* __restrict__ o2, u16* __restrict__ o3) {
  const int bid = blockIdx.x;
  const float* in;
  u16* out;
  int base;
  if (bid < 4096) {
    in = x; out = xb; base = bid * 1024;
  } else {
    const int z = (bid - 4096) >> 8;
    base = ((bid - 4096) & 255) * 1024;
    in = (z == 0) ? w0 : (z == 1) ? w1 : (z == 2) ? w2 : w3;
    out = (z == 0) ? o0 : (z == 1) ? o1 : (z == 2) ? o2 : o3;
  }
  const int i = base + threadIdx.x * 4;
  float4 v = *(const float4*)(in + i);
  ushort4 o;
  o.x = f2bf(v.x); o.y = f2bf(v.y); o.z = f2bf(v.z); o.w = f2bf(v.w);
  *(ushort4*)(out + i) = o;
}

// ---------------------------------------------------------------- QKV GEMM
// Ring-3 pipelined 128x128 tile, BK=32, 4 waves 2x2. Manual vmcnt + raw barrier.
// z=0 -> Q (bf16, scaled log2(e)/8) [B,H,S,D]; z=1 -> K (bf16) [B,H,S,D];
// z=2 -> V^T (f16!) natively (A=Wv, B=x => C[o][r]).
__global__ __launch_bounds__(256, 3)
void qkv_gemm(const u16* __restrict__ xb,
              const u16* __restrict__ wq, const u16* __restrict__ wk, const u16* __restrict__ wv,
              const float* __restrict__ bq, const float* __restrict__ bk, const float* __restrict__ bv,
              u16* __restrict__ Q, u16* __restrict__ K, u16* __restrict__ Vt) {
  __shared__ u16 sA[3][4096];
  __shared__ u16 sB[3][4096];
  const int tid = threadIdx.x;
  const int lane = tid & 63;
  const int wave = tid >> 6;
  const int l15 = lane & 15;
  const int quad = lane >> 4;
  const int wm = wave >> 1, wn = wave & 1;

  const int L = blockIdx.x;            // 0..767
  const int xcd = L & 7;
  const int slot = L >> 3;             // 0..95
  const int bm = xcd * 8 + (slot & 7); // 0..63
  const int r2 = slot >> 3;            // 0..11
  const int bn = r2 & 3;
  const int z = r2 >> 2;

  const float* bias = (z == 0) ? bq : (z == 1) ? bk : bv;
  const float scale = (z == 0) ? 0.18033688011112042f : 1.0f;  // log2(e)/8

  const u16* Arows = (z == 2) ? wv : xb;
  const u16* Brows = (z == 2) ? xb : ((z == 0) ? wq : wk);
  const int am0 = (z == 2) ? (bn * 128) : (bm * 128);
  const int bn0 = (z == 2) ? (bm * 128) : (bn * 128);

  const int srow = tid >> 2;
  const int sg = (tid & 3) ^ ((srow >> 1) & 3);
  const u16* gA = Arows + (am0 + srow) * 512 + sg * 8;
  const u16* gB = Brows + (bn0 + srow) * 512 + sg * 8;

  const int fsw = (quad ^ ((l15 >> 1) & 3)) * 8;
  int aoff[4], boff[4];
#pragma unroll
  for (int t = 0; t < 4; ++t) {
    aoff[t] = (wm * 64 + t * 16 + l15) * 32 + fsw;
    boff[t] = (wn * 64 + t * 16 + l15) * 32 + fsw;
  }

  f32x4 acc[4][4] = {};

#pragma unroll
  for (int t = 0; t < 2; ++t) {
    const int k0 = t * 32;
    gl_lds16(gA + k0, &sA[t][wave * 512]);
    gl_lds16(gA + k0 + 64 * 512, &sA[t][2048 + wave * 512]);
    gl_lds16(gB + k0, &sB[t][wave * 512]);
    gl_lds16(gB + k0 + 64 * 512, &sB[t][2048 + wave * 512]);
  }

  for (int kk = 0; kk < 16; ++kk) {
    WAIT_VM4();
    PIPE_BARRIER();
    {
      const int tp = (kk + 2 < 16) ? kk + 2 : 15;
      const int ns = (kk + 2) % 3;
      const int k0 = tp * 32;
      gl_lds16(gA + k0, &sA[ns][wave * 512]);
      gl_lds16(gA + k0 + 64 * 512, &sA[ns][2048 + wave * 512]);
      gl_lds16(gB + k0, &sB[ns][wave * 512]);
      gl_lds16(gB + k0 + 64 * 512, &sB[ns][2048 + wave * 512]);
    }
    const int cur = kk % 3;
    short8 af[4], bf[4];
#pragma unroll
    for (int t = 0; t < 4; ++t) af[t] = *(const short8*)&sA[cur][aoff[t]];
#pragma unroll
    for (int t = 0; t < 4; ++t) bf[t] = *(const short8*)&sB[cur][boff[t]];
#pragma unroll
    for (int mi = 0; mi < 4; ++mi)
#pragma unroll
      for (int ni = 0; ni < 4; ++ni)
        acc[mi][ni] = MFMA16(af[mi], bf[ni], acc[mi][ni]);
  }

  if (z != 2) {
    u16* dst = (z == 0) ? Q : K;
#pragma unroll
    for (int mi = 0; mi < 4; ++mi) {
#pragma unroll
      for (int ni = 0; ni < 4; ++ni) {
        const int col = bn0 + wn * 64 + ni * 16 + l15;
        const float bs = bias[col];
#pragma unroll
        for (int i = 0; i < 4; ++i) {
          const int row = am0 + wm * 64 + mi * 16 + quad * 4 + i;
          const float v = (acc[mi][ni][i] + bs) * scale;
          const int b = row >> 11, s = row & 2047;
          const int h = col >> 6, d = col & 63;
          dst[(((size_t)(b * 8 + h) * 2048 + s) << 6) + d] = f2bf(v);
        }
      }
    }
  } else {
#pragma unroll
    for (int mi = 0; mi < 4; ++mi) {
#pragma unroll
      for (int i = 0; i < 4; ++i) {
        const int o = am0 + wm * 64 + mi * 16 + quad * 4 + i;
        const float bs = bias[o];
        const int h = o >> 6, d = o & 63;
#pragma unroll
        for (int ni = 0; ni < 4; ++ni) {
          const int r = bn0 + wn * 64 + ni * 16 + l15;
          const int b = r >> 11, s = r & 2047;
          Vt[(((size_t)(b * 8 + h) * 64 + d) << 11) + s] = f2h(acc[mi][ni][i] + bs);
        }
      }
    }
  }
}

// ---------------------------------------------------------------- attention
// Register-resident flash attention, NO LDS in main loop.
// Block = 256 thr (4 waves) = 128 Q-rows of one (bh,qt). Wave pairs split rows
// (64 each); within a pair, waves split t (disjoint 32-t strips). S^T trick:
// scores computed transposed (A=K, B=Q) so the C-layout (row on lane&15, t on
// quad*4+i) IS the A-layout of mfma_f32_16x16x16f16 -> P stays in registers
// (exp2 -> cvt_pkrtz f16). V stored f16 [B,H,D,S]. K/V frags double-buffered
// registers straight from global (L2-resident). Partial oacc/lsum combined
// through LDS once at the end.
__global__ __launch_bounds__(256, 2)
void attn(const u16* __restrict__ Q, const u16* __restrict__ K,
          const u16* __restrict__ Vt, u16* __restrict__ ctx) {
  __shared__ float cbuf[2][64][65];
  __shared__ float lbuf[2][64];
  const int tid = threadIdx.x;
  const int lane = tid & 63;
  const int wave = tid >> 6;     // 0..3
  const int l15 = lane & 15;
  const int quad = lane >> 4;
  const int pair = wave >> 1;    // rows pair*64..+63
  const int par = wave & 1;      // t parity

  const int L = blockIdx.x;           // 0..511
  const int xcd = L & 7;
  const int slot = L >> 3;
  const int bh = xcd * 4 + (slot & 3);
  const int qt = slot >> 2;           // 0..15

  const u16* Qb = Q + (size_t)bh * SS * HD;
  const u16* Kb = K + (size_t)bh * SS * HD;
  const u16* Vb = Vt + (size_t)bh * HD * SS;

  // Q B-fragments: 4 rf x 16 rows (row on lane&15), d = kc*32 + quad*8..+7
  const int rowbase = qt * 128 + pair * 64;
  short8 qf[4][2];
#pragma unroll
  for (int rf = 0; rf < 4; ++rf)
#pragma unroll
    for (int kc = 0; kc < 2; ++kc)
      qf[rf][kc] = *(const short8*)(Qb + (rowbase + rf * 16 + l15) * 64 + kc * 32 + quad * 8);

  f32x4 oacc[4][4] = {};
  float plsum[4] = {0.f, 0.f, 0.f, 0.f};

  // K A-frag: [tblk][kc] lane: t = l15, d = kc*32+quad*8  (16B/lane)
  // V B-frag: [tblk][nd] lane: dv = nd*16+l15, t = tblk*16+quad*4 (8B/lane, f16)
  const u16* kbase = Kb + l15 * 64 + quad * 8;
  const u16* vbase = Vb + l15 * 2048 + quad * 4;

  short8 kf[2][2][2];
  uint2v vf[2][2][4];

#define LOADKV(buf, t0)                                                          \
  do {                                                                           \
    _Pragma("unroll") for (int tb = 0; tb < 2; ++tb) {                           \
      _Pragma("unroll") for (int kc = 0; kc < 2; ++kc)                           \
        kf[buf][tb][kc] = *(const short8*)(kbase + ((t0) + tb * 16) * 64 + kc * 32); \
      _Pragma("unroll") for (int nd = 0; nd < 4; ++nd)                           \
        vf[buf][tb][nd] = *(const uint2v*)(vbase + nd * 16 * 2048 + (t0) + tb * 16); \
    }                                                                            \
  } while (0)

  LOADKV(0, par * 32);

  for (int round = 0; round < 32; ++round) {
    const int cur = round & 1;
    if (round < 31) {
      const int nt0 = (round + 1) * 64 + par * 32;
      LOADKV(cur ^ 1, nt0);
    }

#pragma unroll
    for (int tb = 0; tb < 2; ++tb) {
      // S^T = K Q^T  (D: row=t on quad*4+i, col=Q-row on lane&15)
      f32x4 sacc[4] = {};
#pragma unroll
      for (int rf = 0; rf < 4; ++rf) {
        sacc[rf] = MFMA16(kf[cur][tb][0], qf[rf][0], sacc[rf]);
        sacc[rf] = MFMA16(kf[cur][tb][1], qf[rf][1], sacc[rf]);
      }
#pragma unroll
      for (int rf = 0; rf < 4; ++rf) {
        const float p0 = __builtin_amdgcn_exp2f(sacc[rf][0]);
        const float p1 = __builtin_amdgcn_exp2f(sacc[rf][1]);
        const float p2 = __builtin_amdgcn_exp2f(sacc[rf][2]);
        const float p3 = __builtin_amdgcn_exp2f(sacc[rf][3]);
        plsum[rf] += (p0 + p1) + (p2 + p3);
        uint2v pu;
        pu.x = __builtin_bit_cast(unsigned int, __builtin_amdgcn_cvt_pkrtz(p0, p1));
        pu.y = __builtin_bit_cast(unsigned int, __builtin_amdgcn_cvt_pkrtz(p2, p3));
        const f16x4 pf = __builtin_bit_cast(f16x4, pu);
#pragma unroll
        for (int nd = 0; nd < 4; ++nd)
          oacc[rf][nd] = MFMAH16(pf, __builtin_bit_cast(f16x4, vf[cur][tb][nd]),
                                 oacc[rf][nd]);
      }
    }
  }

  // quad-reduce row sums (row = l15 after reduction, all lanes valid)
#pragma unroll
  for (int rf = 0; rf < 4; ++rf) {
    plsum[rf] += __shfl_xor(plsum[rf], 16);
    plsum[rf] += __shfl_xor(plsum[rf], 32);
  }

  // cross-wave (pair) combine via LDS
  if (par) {
#pragma unroll
    for (int rf = 0; rf < 4; ++rf) {
#pragma unroll
      for (int nd = 0; nd < 4; ++nd)
#pragma unroll
        for (int i = 0; i < 4; ++i)
          cbuf[pair][rf * 16 + quad * 4 + i][nd * 16 + l15] = oacc[rf][nd][i];
      if (quad == 0) lbuf[pair][rf * 16 + l15] = plsum[rf];
    }
  }
  __syncthreads();
  if (!par) {
    const int b = bh >> 3, h = bh & 7;
#pragma unroll
    for (int rf = 0; rf < 4; ++rf) {
      const float tot = plsum[rf] + lbuf[pair][rf * 16 + l15];
      float inv[4];
#pragma unroll
      for (int i = 0; i < 4; ++i)
        inv[i] = __builtin_amdgcn_rcpf(__shfl(tot, (quad << 4) + quad * 4 + i));
#pragma unroll
      for (int nd = 0; nd < 4; ++nd)
#pragma unroll
        for (int i = 0; i < 4; ++i) {
          const float v = (oacc[rf][nd][i] +
                           cbuf[pair][rf * 16 + quad * 4 + i][nd * 16 + l15]) * inv[i];
          const int s = rowbase + rf * 16 + quad * 4 + i;
          const int d = nd * 16 + l15;
          ctx[((size_t)(b * 2048 + s) << 9) + h * 64 + d] = f2bf(v);
        }
    }
  }
}

// ---------------------------------------------------------------- out GEMM
// Ring-3 pipelined 128x64 tiles; manual vmcnt(3) + raw barrier; XCD-clustered bm.
__global__ __launch_bounds__(256, 2)
void out_gemm(const u16* __restrict__ A, const u16* __restrict__ W,
              const float* __restrict__ bias, float* __restrict__ out) {
  __shared__ u16 sA[3][4096];
  __shared__ u16 sB[3][2048];
  const int tid = threadIdx.x;
  const int lane = tid & 63;
  const int wave = tid >> 6;
  const int l15 = lane & 15;
  const int quad = lane >> 4;

  const int L = blockIdx.x;
  const int xcd = L & 7;
  const int slot = L >> 3;
  const int bm = xcd * 8 + (slot & 7);
  const int bn = slot >> 3;

  const int srow = tid >> 2;
  const int sg = (tid & 3) ^ ((srow >> 1) & 3);
  const u16* gA = A + (bm * 128 + srow) * 512 + sg * 8;
  const u16* gB = W + (bn * 64 + srow) * 512 + sg * 8;

  const int fsw = (quad ^ ((l15 >> 1) & 3)) * 8;
  int aoff[2], boff[4];
#pragma unroll
  for (int t = 0; t < 2; ++t) aoff[t] = (wave * 32 + t * 16 + l15) * 32 + fsw;
#pragma unroll
  for (int t = 0; t < 4; ++t) boff[t] = (t * 16 + l15) * 32 + fsw;

  f32x4 acc[2][4] = {};

#pragma unroll
  for (int t = 0; t < 2; ++t) {
    const int k0 = t * 32;
    gl_lds16(gA + k0, &sA[t][wave * 512]);
    gl_lds16(gA + k0 + 64 * 512, &sA[t][2048 + wave * 512]);
    gl_lds16(gB + k0, &sB[t][wave * 512]);
  }

  for (int kk = 0; kk < 16; ++kk) {
    WAIT_VM3();
    PIPE_BARRIER();
    {
      const int tp = (kk + 2 < 16) ? kk + 2 : 15;
      const int ns = (kk + 2) % 3;
      const int k0 = tp * 32;
      gl_lds16(gA + k0, &sA[ns][wave * 512]);
      gl_lds16(gA + k0 + 64 * 512, &sA[ns][2048 + wave * 512]);
      gl_lds16(gB + k0, &sB[ns][wave * 512]);
    }
    const int cur = kk % 3;
    short8 af[2], bf[4];
#pragma unroll
    for (int t = 0; t < 2; ++t) af[t] = *(const short8*)&sA[cur][aoff[t]];
#pragma unroll
    for (int t = 0; t < 4; ++t) bf[t] = *(const short8*)&sB[cur][boff[t]];
#pragma unroll
    for (int mi = 0; mi < 2; ++mi)
#pragma unroll
      for (int ni = 0; ni < 4; ++ni)
        acc[mi][ni] = MFMA16(af[mi], bf[ni], acc[mi][ni]);
  }

#pragma unroll
  for (int mi = 0; mi < 2; ++mi) {
#pragma unroll
    for (int ni = 0; ni < 4; ++ni) {
      const int col = bn * 64 + ni * 16 + l15;
      const float bs = bias[col];
#pragma unroll
      for (int i = 0; i < 4; ++i) {
        const int row = bm * 128 + wave * 32 + mi * 16 + quad * 4 + i;
        out[(size_t)row * 512 + col] = acc[mi][ni][i] + bs;
      }
    }
  }
}

// ---------------------------------------------------------------- launch
extern "C" void kernel_launch(void* const* d_in, const int* in_sizes, int n_in,
                              void* d_out, int out_size, void* d_ws, size_t ws_size,
                              hipStream_t stream) {
  const float* x = (const float*)d_in[0];
  const float* Wq = (const float*)d_in[1];
  const float* bq = (const float*)d_in[2];
  const float* Wk = (const float*)d_in[3];
  const float* bk = (const float*)d_in[4];
  const float* Wv = (const float*)d_in[5];
  const float* bv = (const float*)d_in[6];
  const float* Wo = (const float*)d_in[7];
  const float* bo = (const float*)d_in[8];
  float* out = (float*)d_out;

  char* ws = (char*)d_ws;
  u16* xb  = (u16*)(ws);                               // 8 MiB
  u16* wqb = (u16*)(ws + (8u << 20));                  // 512 KiB each
  u16* wkb = (u16*)(ws + (8u << 20) + (512u << 10));
  u16* wvb = (u16*)(ws + (9u << 20));
  u16* wob = (u16*)(ws + (9u << 20) + (512u << 10));
  u16* Qb  = (u16*)(ws + (10u << 20));                 // 8 MiB [B,H,S,D] bf16 * log2e/8
  u16* Kb  = (u16*)(ws + (18u << 20));                 // 8 MiB [B,H,S,D] bf16
  u16* Vtb = (u16*)(ws + (26u << 20));                 // 8 MiB [B,H,D,S] f16
  u16* ctx = (u16*)(ws + (34u << 20));                 // 8 MiB [B,S,HID] bf16

  prep<<<5120, 256, 0, stream>>>(x, Wq, Wk, Wv, Wo, xb, wqb, wkb, wvb, wob);
  qkv_gemm<<<768, 256, 0, stream>>>(xb, wqb, wkb, wvb, bq, bk, bv, Qb, Kb, Vtb);
  attn<<<512, 256, 0, stream>>>(Qb, Kb, Vtb, ctx);
  out_gemm<<<512, 256, 0, stream>>>(ctx, wob, bo, out);
}

// Round 8
// 156.366 us; speedup vs baseline: 11.9853x; 11.9853x over previous
//
#include <hip/hip_runtime.h>
#include <stdint.h>

#define HID 512
#define NH 8
#define HD 64
#define BB 4
#define SS 2048

typedef unsigned short u16;
typedef __attribute__((ext_vector_type(8))) short short8;
typedef __attribute__((ext_vector_type(4))) float f32x4;
typedef __attribute__((ext_vector_type(4))) _Float16 f16x4;
typedef __attribute__((ext_vector_type(2))) unsigned int uint2v;

#define MFMA16(a, b, c) __builtin_amdgcn_mfma_f32_16x16x32_bf16((a), (b), (c), 0, 0, 0)
#define MFMAH16(a, b, c) __builtin_amdgcn_mfma_f32_16x16x16f16((a), (b), (c), 0, 0, 0)

// s_waitcnt encodings: lgkmcnt(15)=0xF00 | expcnt(7)=0x70 | vmcnt low4
#define WAIT_VM4() __builtin_amdgcn_s_waitcnt(0xF74)
#define WAIT_VM3() __builtin_amdgcn_s_waitcnt(0xF73)
#define WAIT_VM0() __builtin_amdgcn_s_waitcnt(0xF70)
#define PIPE_BARRIER() do { asm volatile("" ::: "memory"); \
  __builtin_amdgcn_s_barrier(); asm volatile("" ::: "memory"); } while (0)

__device__ __forceinline__ u16 f2bf(float f) {
  union { float f; uint32_t u; } v; v.f = f;
  return (u16)((v.u + 0x7fffu + ((v.u >> 16) & 1u)) >> 16);
}

__device__ __forceinline__ u16 f2h(float f) {
  _Float16 h = (_Float16)f;
  return __builtin_bit_cast(u16, h);
}

__device__ __forceinline__ void gl_lds16(const u16* g, u16* l) {
  __builtin_amdgcn_global_load_lds(
      (const __attribute__((address_space(1))) unsigned int*)g,
      (__attribute__((address_space(3))) unsigned int*)l, 16, 0, 0);
}

// ---------------------------------------------------------------- prep
__global__ void prep(const float* __restrict__ x,
                     const float* __restrict__ w0, const float* __restrict__ w1,
                     const float* __restrict__ w2, const float* __restrict__ w3,
                     u16* __restrict__ xb,
                     u16* __restrict__ o0, u16* __restrict__ o1,
                     u16* __restrict__ o2, u16* __restrict__ o3) {
  const int bid = blockIdx.x;
  const float* in;
  u16* out;
  int base;
  if (bid < 4096) {
    in = x; out = xb; base = bid * 1024;
  } else {
    const int z = (bid - 4096) >> 8;
    base = ((bid - 4096) & 255) * 1024;
    in = (z == 0) ? w0 : (z == 1) ? w1 : (z == 2) ? w2 : w3;
    out = (z == 0) ? o0 : (z == 1) ? o1 : (z == 2) ? o2 : o3;
  }
  const int i = base + threadIdx.x * 4;
  float4 v = *(const float4*)(in + i);
  ushort4 o;
  o.x = f2bf(v.x); o.y = f2bf(v.y); o.z = f2bf(v.z); o.w = f2bf(v.w);
  *(ushort4*)(out + i) = o;
}

// ---------------------------------------------------------------- QKV GEMM
// Ring-3 pipelined 128x128 tile, BK=32, 4 waves 2x2. Manual vmcnt + raw barrier.
// z=0 -> Q (bf16, scaled log2(e)/8) [B,H,S,D]; z=1 -> K (bf16) [B,H,S,D];
// z=2 -> V^T (f16) natively (A=Wv, B=x => C[o][r]).
__global__ __launch_bounds__(256, 3)
void qkv_gemm(const u16* __restrict__ xb,
              const u16* __restrict__ wq, const u16* __restrict__ wk, const u16* __restrict__ wv,
              const float* __restrict__ bq, const float* __restrict__ bk, const float* __restrict__ bv,
              u16* __restrict__ Q, u16* __restrict__ K, u16* __restrict__ Vt) {
  __shared__ u16 sA[3][4096];
  __shared__ u16 sB[3][4096];
  const int tid = threadIdx.x;
  const int lane = tid & 63;
  const int wave = tid >> 6;
  const int l15 = lane & 15;
  const int quad = lane >> 4;
  const int wm = wave >> 1, wn = wave & 1;

  const int L = blockIdx.x;            // 0..767
  const int xcd = L & 7;
  const int slot = L >> 3;             // 0..95
  const int bm = xcd * 8 + (slot & 7); // 0..63
  const int r2 = slot >> 3;            // 0..11
  const int bn = r2 & 3;
  const int z = r2 >> 2;

  const float* bias = (z == 0) ? bq : (z == 1) ? bk : bv;
  const float scale = (z == 0) ? 0.18033688011112042f : 1.0f;  // log2(e)/8

  const u16* Arows = (z == 2) ? wv : xb;
  const u16* Brows = (z == 2) ? xb : ((z == 0) ? wq : wk);
  const int am0 = (z == 2) ? (bn * 128) : (bm * 128);
  const int bn0 = (z == 2) ? (bm * 128) : (bn * 128);

  const int srow = tid >> 2;
  const int sg = (tid & 3) ^ ((srow >> 1) & 3);
  const u16* gA = Arows + (am0 + srow) * 512 + sg * 8;
  const u16* gB = Brows + (bn0 + srow) * 512 + sg * 8;

  const int fsw = (quad ^ ((l15 >> 1) & 3)) * 8;
  int aoff[4], boff[4];
#pragma unroll
  for (int t = 0; t < 4; ++t) {
    aoff[t] = (wm * 64 + t * 16 + l15) * 32 + fsw;
    boff[t] = (wn * 64 + t * 16 + l15) * 32 + fsw;
  }

  f32x4 acc[4][4] = {};

#pragma unroll
  for (int t = 0; t < 2; ++t) {
    const int k0 = t * 32;
    gl_lds16(gA + k0, &sA[t][wave * 512]);
    gl_lds16(gA + k0 + 64 * 512, &sA[t][2048 + wave * 512]);
    gl_lds16(gB + k0, &sB[t][wave * 512]);
    gl_lds16(gB + k0 + 64 * 512, &sB[t][2048 + wave * 512]);
  }

  for (int kk = 0; kk < 16; ++kk) {
    WAIT_VM4();
    PIPE_BARRIER();
    {
      const int tp = (kk + 2 < 16) ? kk + 2 : 15;
      const int ns = (kk + 2) % 3;
      const int k0 = tp * 32;
      gl_lds16(gA + k0, &sA[ns][wave * 512]);
      gl_lds16(gA + k0 + 64 * 512, &sA[ns][2048 + wave * 512]);
      gl_lds16(gB + k0, &sB[ns][wave * 512]);
      gl_lds16(gB + k0 + 64 * 512, &sB[ns][2048 + wave * 512]);
    }
    const int cur = kk % 3;
    short8 af[4], bf[4];
#pragma unroll
    for (int t = 0; t < 4; ++t) af[t] = *(const short8*)&sA[cur][aoff[t]];
#pragma unroll
    for (int t = 0; t < 4; ++t) bf[t] = *(const short8*)&sB[cur][boff[t]];
#pragma unroll
    for (int mi = 0; mi < 4; ++mi)
#pragma unroll
      for (int ni = 0; ni < 4; ++ni)
        acc[mi][ni] = MFMA16(af[mi], bf[ni], acc[mi][ni]);
  }

  if (z != 2) {
    u16* dst = (z == 0) ? Q : K;
#pragma unroll
    for (int mi = 0; mi < 4; ++mi) {
#pragma unroll
      for (int ni = 0; ni < 4; ++ni) {
        const int col = bn0 + wn * 64 + ni * 16 + l15;
        const float bs = bias[col];
#pragma unroll
        for (int i = 0; i < 4; ++i) {
          const int row = am0 + wm * 64 + mi * 16 + quad * 4 + i;
          const float v = (acc[mi][ni][i] + bs) * scale;
          const int b = row >> 11, s = row & 2047;
          const int h = col >> 6, d = col & 63;
          dst[(((size_t)(b * 8 + h) * 2048 + s) << 6) + d] = f2bf(v);
        }
      }
    }
  } else {
#pragma unroll
    for (int mi = 0; mi < 4; ++mi) {
#pragma unroll
      for (int i = 0; i < 4; ++i) {
        const int o = am0 + wm * 64 + mi * 16 + quad * 4 + i;
        const float bs = bias[o];
        const int h = o >> 6, d = o & 63;
#pragma unroll
        for (int ni = 0; ni < 4; ++ni) {
          const int r = bn0 + wn * 64 + ni * 16 + l15;
          const int b = r >> 11, s = r & 2047;
          Vt[(((size_t)(b * 8 + h) * 64 + d) << 11) + s] = f2h(acc[mi][ni][i] + bs);
        }
      }
    }
  }
}

// ---------------------------------------------------------------- attention
// S^T-trick flash attention, LDS ring-4 staged K/V, P register-resident.
// 512 thr = 8 waves = 4 row-pairs (32 Q-rows each) x 2 t-parities (32-t strips).
// Scores computed transposed (A=K-frag from LDS, B=Q-frag in regs): C-layout
// (qrow on lane&15, t on quad*4+i) IS the A-layout of mfma_f32_16x16x16f16,
// so P goes exp2 -> cvt_pkrtz -> PV MFMA without touching LDS. V is f16
// [B,H,D,S]. Ring-4 x 16KB tiles (64 KB LDS), vmcnt(4) + raw barrier per
// round: wait retires exactly tile tt; issue tt+3 into slot of tt-1 (reads
// done pre-barrier). oacc 32 VGPR/wave -> fits 128-cap at 4 waves/SIMD.
__global__ __launch_bounds__(512, 4)
void attn(const u16* __restrict__ Q, const u16* __restrict__ K,
          const u16* __restrict__ Vt, u16* __restrict__ ctx) {
  __shared__ __align__(16) u16 smem[4 * 8192];  // slot: K[64t][64d] @0, V[64d][64t] @4096
  const int tid = threadIdx.x;
  const int lane = tid & 63;
  const int wave = tid >> 6;
  const int l15 = lane & 15;
  const int quad = lane >> 4;
  const int pair = wave >> 1;   // 0..3: rows pair*32..+31
  const int par = wave & 1;     // t-strip parity

  const int L = blockIdx.x;           // 0..511
  const int xcd = L & 7;
  const int slotb = L >> 3;
  const int bh = xcd * 4 + (slotb & 3);
  const int qt = slotb >> 2;          // 0..15

  const u16* Qb = Q + (size_t)bh * SS * HD;
  const u16* Kb = K + (size_t)bh * SS * HD;
  const u16* Vb = Vt + (size_t)bh * HD * SS;

  // Q B-fragments (regs): qrow = rowbase + rf*16 + l15, d = kc*32 + quad*8
  const int rowbase = qt * 128 + pair * 32;
  short8 qf[2][2];
#pragma unroll
  for (int rf = 0; rf < 2; ++rf)
#pragma unroll
    for (int kc = 0; kc < 2; ++kc)
      qf[rf][kc] = *(const short8*)(Qb + (rowbase + rf * 16 + l15) * 64 + kc * 32 + quad * 8);
  asm volatile("" ::: "memory");  // Q loads oldest in vmcnt queue

  f32x4 oacc[2][4] = {};
  float plsum[2] = {0.f, 0.f};

  // DMA source offsets (swizzle on the global side; LDS dest is linear tid*8)
  const int trow = tid >> 3;                    // 0..63
  const int gsw = (tid & 7) ^ (trow & 7);
  const int kOff = trow * 64 + gsw * 8;         // + tile*4096
  const int vOff = trow * 2048 + gsw * 8;       // + tile*64
  u16* ldsK = smem + tid * 8;                   // + slot*8192
  u16* ldsV = smem + 4096 + tid * 8;

  // fragment LDS offsets (u16 units)
  const int l7 = l15 & 7;
  int kfo[2];  // [kc]; + tb*1024; rows t = par*32 + tb*16 + l15
#pragma unroll
  for (int kc = 0; kc < 2; ++kc)
    kfo[kc] = (par * 32 + l15) * 64 + ((kc * 4 + quad) ^ l7) * 8;
  int vfo[2];  // [tb]; + nd*1024; rows dv = nd*16+l15, t granule par*4+tb*2+(quad>>1)
#pragma unroll
  for (int tb = 0; tb < 2; ++tb)
    vfo[tb] = l15 * 64 + (((par * 4 + tb * 2 + (quad >> 1)) ^ l7) * 8) + (quad & 1) * 4;

  // preload tiles 0..2
#pragma unroll
  for (int t = 0; t < 3; ++t) {
    gl_lds16(Kb + t * 4096 + kOff, ldsK + t * 8192);
    gl_lds16(Vb + t * 64 + vOff, ldsV + t * 8192);
  }

  for (int tt = 0; tt < 32; ++tt) {
    WAIT_VM4();      // retires exactly tile tt (leaves tt+1, tt+2 in flight)
    PIPE_BARRIER();
    {
      const int tp = (tt + 3 < 32) ? tt + 3 : 31;   // clamp -> harmless dup
      const int ns = (tt + 3) & 3;
      gl_lds16(Kb + tp * 4096 + kOff, ldsK + ns * 8192);
      gl_lds16(Vb + tp * 64 + vOff, ldsV + ns * 8192);
    }
    const int cb = (tt & 3) * 8192;

#pragma unroll
    for (int tb = 0; tb < 2; ++tb) {
      // S^T = K Q^T for t-strip par*32 + tb*16
      const short8 k0 = *(const short8*)&smem[cb + tb * 1024 + kfo[0]];
      const short8 k1 = *(const short8*)&smem[cb + tb * 1024 + kfo[1]];
      f32x4 sacc[2] = {};
#pragma unroll
      for (int rf = 0; rf < 2; ++rf) {
        sacc[rf] = MFMA16(k0, qf[rf][0], sacc[rf]);
        sacc[rf] = MFMA16(k1, qf[rf][1], sacc[rf]);
      }
      // V B-frags for this t-strip
      uint2v vf[4];
#pragma unroll
      for (int nd = 0; nd < 4; ++nd)
        vf[nd] = *(const uint2v*)&smem[cb + 4096 + nd * 1024 + vfo[tb]];
#pragma unroll
      for (int rf = 0; rf < 2; ++rf) {
        const float p0 = __builtin_amdgcn_exp2f(sacc[rf][0]);
        const float p1 = __builtin_amdgcn_exp2f(sacc[rf][1]);
        const float p2 = __builtin_amdgcn_exp2f(sacc[rf][2]);
        const float p3 = __builtin_amdgcn_exp2f(sacc[rf][3]);
        plsum[rf] += (p0 + p1) + (p2 + p3);
        uint2v pu;
        pu.x = __builtin_bit_cast(unsigned int, __builtin_amdgcn_cvt_pkrtz(p0, p1));
        pu.y = __builtin_bit_cast(unsigned int, __builtin_amdgcn_cvt_pkrtz(p2, p3));
        const f16x4 pf = __builtin_bit_cast(f16x4, pu);
#pragma unroll
        for (int nd = 0; nd < 4; ++nd)
          oacc[rf][nd] = MFMAH16(pf, __builtin_bit_cast(f16x4, vf[nd]), oacc[rf][nd]);
      }
    }
  }

  // drain in-flight dup DMAs (they write ring slots we are about to reuse)
  WAIT_VM0();
  __syncthreads();

  // reduce partial row sums across quads: lane l15 -> sum for qrow rf*16+l15
#pragma unroll
  for (int rf = 0; rf < 2; ++rf) {
    plsum[rf] += __shfl_xor(plsum[rf], 16);
    plsum[rf] += __shfl_xor(plsum[rf], 32);
  }

  float* cbuf = (float*)smem;          // [128 rows][68]
  float* lbuf = cbuf + 128 * 68;       // [128]
  if (par) {
#pragma unroll
    for (int rf = 0; rf < 2; ++rf) {
#pragma unroll
      for (int nd = 0; nd < 4; ++nd)
#pragma unroll
        for (int i = 0; i < 4; ++i)
          cbuf[(pair * 32 + rf * 16 + quad * 4 + i) * 68 + nd * 16 + l15] = oacc[rf][nd][i];
      if (quad == 0) lbuf[pair * 32 + rf * 16 + l15] = plsum[rf];
    }
  }
  __syncthreads();
  if (!par) {
    const int b = bh >> 3, h = bh & 7;
#pragma unroll
    for (int rf = 0; rf < 2; ++rf) {
      const float tot = plsum[rf] + lbuf[pair * 32 + rf * 16 + l15];
      float inv[4];
#pragma unroll
      for (int i = 0; i < 4; ++i)
        inv[i] = __builtin_amdgcn_rcpf(__shfl(tot, quad * 4 + i));
#pragma unroll
      for (int nd = 0; nd < 4; ++nd)
#pragma unroll
        for (int i = 0; i < 4; ++i) {
          const float v = (oacc[rf][nd][i] +
                           cbuf[(pair * 32 + rf * 16 + quad * 4 + i) * 68 + nd * 16 + l15]) * inv[i];
          const int s = rowbase + rf * 16 + quad * 4 + i;
          const int d = nd * 16 + l15;
          ctx[((size_t)(b * 2048 + s) << 9) + h * 64 + d] = f2bf(v);
        }
    }
  }
}

// ---------------------------------------------------------------- out GEMM
// Ring-3 pipelined 128x64 tiles; manual vmcnt(3) + raw barrier; XCD-clustered bm.
__global__ __launch_bounds__(256, 2)
void out_gemm(const u16* __restrict__ A, const u16* __restrict__ W,
              const float* __restrict__ bias, float* __restrict__ out) {
  __shared__ u16 sA[3][4096];
  __shared__ u16 sB[3][2048];
  const int tid = threadIdx.x;
  const int lane = tid & 63;
  const int wave = tid >> 6;
  const int l15 = lane & 15;
  const int quad = lane >> 4;

  const int L = blockIdx.x;
  const int xcd = L & 7;
  const int slot = L >> 3;
  const int bm = xcd * 8 + (slot & 7);
  const int bn = slot >> 3;

  const int srow = tid >> 2;
  const int sg = (tid & 3) ^ ((srow >> 1) & 3);
  const u16* gA = A + (bm * 128 + srow) * 512 + sg * 8;
  const u16* gB = W + (bn * 64 + srow) * 512 + sg * 8;

  const int fsw = (quad ^ ((l15 >> 1) & 3)) * 8;
  int aoff[2], boff[4];
#pragma unroll
  for (int t = 0; t < 2; ++t) aoff[t] = (wave * 32 + t * 16 + l15) * 32 + fsw;
#pragma unroll
  for (int t = 0; t < 4; ++t) boff[t] = (t * 16 + l15) * 32 + fsw;

  f32x4 acc[2][4] = {};

#pragma unroll
  for (int t = 0; t < 2; ++t) {
    const int k0 = t * 32;
    gl_lds16(gA + k0, &sA[t][wave * 512]);
    gl_lds16(gA + k0 + 64 * 512, &sA[t][2048 + wave * 512]);
    gl_lds16(gB + k0, &sB[t][wave * 512]);
  }

  for (int kk = 0; kk < 16; ++kk) {
    WAIT_VM3();
    PIPE_BARRIER();
    {
      const int tp = (kk + 2 < 16) ? kk + 2 : 15;
      const int ns = (kk + 2) % 3;
      const int k0 = tp * 32;
      gl_lds16(gA + k0, &sA[ns][wave * 512]);
      gl_lds16(gA + k0 + 64 * 512, &sA[ns][2048 + wave * 512]);
      gl_lds16(gB + k0, &sB[ns][wave * 512]);
    }
    const int cur = kk % 3;
    short8 af[2], bf[4];
#pragma unroll
    for (int t = 0; t < 2; ++t) af[t] = *(const short8*)&sA[cur][aoff[t]];
#pragma unroll
    for (int t = 0; t < 4; ++t) bf[t] = *(const short8*)&sB[cur][boff[t]];
#pragma unroll
    for (int mi = 0; mi < 2; ++mi)
#pragma unroll
      for (int ni = 0; ni < 4; ++ni)
        acc[mi][ni] = MFMA16(af[mi], bf[ni], acc[mi][ni]);
  }

#pragma unroll
  for (int mi = 0; mi < 2; ++mi) {
#pragma unroll
    for (int ni = 0; ni < 4; ++ni) {
      const int col = bn * 64 + ni * 16 + l15;
      const float bs = bias[col];
#pragma unroll
      for (int i = 0; i < 4; ++i) {
        const int row = bm * 128 + wave * 32 + mi * 16 + quad * 4 + i;
        out[(size_t)row * 512 + col] = acc[mi][ni][i] + bs;
      }
    }
  }
}

// ---------------------------------------------------------------- launch
extern "C" void kernel_launch(void* const* d_in, const int* in_sizes, int n_in,
                              void* d_out, int out_size, void* d_ws, size_t ws_size,
                              hipStream_t stream) {
  const float* x = (const float*)d_in[0];
  const float* Wq = (const float*)d_in[1];
  const float* bq = (const float*)d_in[2];
  const float* Wk = (const float*)d_in[3];
  const float* bk = (const float*)d_in[4];
  const float* Wv = (const float*)d_in[5];
  const float* bv = (const float*)d_in[6];
  const float* Wo = (const float*)d_in[7];
  const float* bo = (const float*)d_in[8];
  float* out = (float*)d_out;

  char* ws = (char*)d_ws;
  u16* xb  = (u16*)(ws);                               // 8 MiB
  u16* wqb = (u16*)(ws + (8u << 20));                  // 512 KiB each
  u16* wkb = (u16*)(ws + (8u << 20) + (512u << 10));
  u16* wvb = (u16*)(ws + (9u << 20));
  u16* wob = (u16*)(ws + (9u << 20) + (512u << 10));
  u16* Qb  = (u16*)(ws + (10u << 20));                 // 8 MiB [B,H,S,D] bf16 * log2e/8
  u16* Kb  = (u16*)(ws + (18u << 20));                 // 8 MiB [B,H,S,D] bf16
  u16* Vtb = (u16*)(ws + (26u << 20));                 // 8 MiB [B,H,D,S] f16
  u16* ctx = (u16*)(ws + (34u << 20));                 // 8 MiB [B,S,HID] bf16

  prep<<<5120, 256, 0, stream>>>(x, Wq, Wk, Wv, Wo, xb, wqb, wkb, wvb, wob);
  qkv_gemm<<<768, 256, 0, stream>>>(xb, wqb, wkb, wvb, bq, bk, bv, Qb, Kb, Vtb);
  attn<<<512, 512, 0, stream>>>(Qb, Kb, Vtb, ctx);
  out_gemm<<<512, 256, 0, stream>>>(ctx, wob, bo, out);
}